// Round 5
// baseline (262.806 us; speedup 1.0000x reference)
//
#include <hip/hip_runtime.h>
#include <hip/hip_bf16.h>
#include <math.h>

#define N_NODES 100000
#define N_EDGES 1600000
#define HEADS 8
#define CH 16
#define HC 128
#define NEG_SLOPE 0.2f
#define TOTAL_E (N_EDGES + N_NODES)

#define DPB 128                          // dests per bucket
#define NB  ((N_NODES + DPB - 1) / DPB)  // 782 buckets
#define NCH 128                          // fat chunks -> 64B runs per (chunk,bucket)
#define EPC ((N_EDGES + NCH - 1) / NCH)  // 12500
#define CAPS 3072                        // per-bucket CSR stage (max load ~2450)

// ---------------- K1: node transform + zero bucket histogram -------------------
__global__ __launch_bounds__(256) void k_node(
    const float* __restrict__ x, const float* __restrict__ W,
    const float* __restrict__ att_s, const float* __restrict__ att_d,
    __hip_bfloat162* __restrict__ h, float* __restrict__ a_src,
    float* __restrict__ a_dst, int* __restrict__ bhist) {
    __shared__ float sW[16 * HC];
    int t = threadIdx.x;
    if (blockIdx.x == 0)                       // zero hist; k_hist runs next launch
        for (int i = t; i < NB; i += 256) bhist[i] = 0;
    for (int i = t; i < 16 * HC; i += 256) sW[i] = W[i];
    __syncthreads();
    int lane = t & 63;
    int gw = blockIdx.x * 4 + (t >> 6);
    int nw = gridDim.x * 4;
    int c0 = 2 * lane;
    float as0 = att_s[c0], as1 = att_s[c0 + 1];
    float ad0 = att_d[c0], ad1 = att_d[c0 + 1];
    for (int node = gw; node < N_NODES; node += nw) {
        float xv = 0.f;
        if (lane < 16) xv = x[node * 16 + lane];
        float acc0 = 0.f, acc1 = 0.f;
#pragma unroll
        for (int k = 0; k < 16; ++k) {
            float xk = __shfl(xv, k);
            acc0 = fmaf(xk, sW[k * HC + c0], acc0);
            acc1 = fmaf(xk, sW[k * HC + c0 + 1], acc1);
        }
        h[node * 64 + lane] = __float22bfloat162_rn(float2{acc0, acc1});
        float ps = acc0 * as0 + acc1 * as1;
        float pd = acc0 * ad0 + acc1 * ad1;
#pragma unroll
        for (int off = 4; off >= 1; off >>= 1) {
            ps += __shfl_xor(ps, off);
            pd += __shfl_xor(pd, off);
        }
        if ((lane & 7) == 0) {
            int hd = lane >> 3;
            a_src[node * HEADS + hd] = ps;
            a_dst[node * HEADS + hd] = pd;
        }
    }
}

// ---------------- K2: global bucket histogram ----------------------------------
__global__ __launch_bounds__(256) void k_hist(const int* __restrict__ ei,
                                              int* __restrict__ bhist) {
    __shared__ int lh[NB];
    int t = threadIdx.x;
    for (int b = t; b < NB; b += 256) lh[b] = 0;
    __syncthreads();
    for (int e = blockIdx.x * 256 + t; e < N_EDGES; e += gridDim.x * 256)
        atomicAdd(&lh[ei[N_EDGES + e] >> 7], 1);
    __syncthreads();
    for (int b = t; b < NB; b += 256) if (lh[b]) atomicAdd(&bhist[b], lh[b]);
}

// ---------------- K3: scan bucket totals (wave-shuffle, 1 block) ---------------
__global__ __launch_bounds__(1024) void k_scan_top(const int* __restrict__ bhist,
                                                   int* __restrict__ sbase,
                                                   int* __restrict__ gcur,
                                                   int* __restrict__ offsets) {
    __shared__ int ws[16];
    int t = threadIdx.x, lane = t & 63, w = t >> 6;
    int v = (t < NB) ? bhist[t] : 0;
    int inc = v;
#pragma unroll
    for (int off = 1; off < 64; off <<= 1) {
        int y = __shfl_up(inc, off);
        if (lane >= off) inc += y;
    }
    if (lane == 63) ws[w] = inc;
    __syncthreads();
    if (w == 0) {
        int s = (lane < 16) ? ws[lane] : 0;
#pragma unroll
        for (int off = 1; off < 16; off <<= 1) {
            int y = __shfl_up(s, off);
            if (lane >= off) s += y;
        }
        if (lane < 16) ws[lane] = s;          // inclusive wave sums
    }
    __syncthreads();
    int base = (w > 0) ? ws[w - 1] : 0;
    if (t < NB) {
        int excl = base + inc - v;
        sbase[t] = excl;
        gcur[t] = excl;
    }
    if (t == 0) { sbase[NB] = N_EDGES; offsets[N_NODES] = TOTAL_E; }
}

// ---------------- K4: place edges into bucket-partitioned staging --------------
// per-(block,bucket) contiguous run reserved via one global atomic -> 64B runs
__global__ __launch_bounds__(256) void k_place(const int* __restrict__ ei,
                                               int* __restrict__ gcur,
                                               unsigned* __restrict__ stg) {
    __shared__ int cnt[NB];
    __shared__ int curb[NB];
    int t = threadIdx.x, c = blockIdx.x;
    for (int b = t; b < NB; b += 256) cnt[b] = 0;
    __syncthreads();
    int beg = c * EPC, end = beg + EPC; if (end > N_EDGES) end = N_EDGES;
    for (int e = beg + t; e < end; e += 256)
        atomicAdd(&cnt[ei[N_EDGES + e] >> 7], 1);
    __syncthreads();
    for (int b = t; b < NB; b += 256) {
        int n = cnt[b];
        curb[b] = n ? atomicAdd(&gcur[b], n) : 0;
    }
    __syncthreads();
    for (int e = beg + t; e < end; e += 256) {
        unsigned src = (unsigned)ei[e];
        int dst = ei[N_EDGES + e];
        int pos = atomicAdd(&curb[dst >> 7], 1);
        stg[pos] = ((unsigned)(dst & 127) << 17) | src;   // src < 2^17
    }
}

// ---------------- K5: per-bucket CSR finalize (one block per bucket) -----------
__global__ __launch_bounds__(256) void k_build(const unsigned* __restrict__ stg,
                                               const int* __restrict__ sbase,
                                               int* __restrict__ offsets,
                                               int* __restrict__ csr_src) {
    __shared__ int hist[DPB];
    __shared__ int wsum_s[2];
    __shared__ int cstage[CAPS];
    int b = blockIdx.x, t = threadIdx.x;
    int sb = sbase[b], ecnt = sbase[b + 1] - sb;
    int d0 = b << 7;
    int selfc = N_NODES - d0; if (selfc > DPB) selfc = DPB;
    int total = ecnt + selfc;
    bool fits = total <= CAPS;
    int cbase = sb + d0;                 // earlier buckets' edges + self loops
    bool valid = (t < DPB) && (d0 + t < N_NODES);
    if (t < DPB) hist[t] = valid ? 1 : 0;
    __syncthreads();
    for (int i = t; i < ecnt; i += 256) atomicAdd(&hist[stg[sb + i] >> 17], 1);
    __syncthreads();
    // exclusive scan of hist[0..127] with 2 waves (shuffle)
    int lane = t & 63, w = t >> 6;
    int v = (t < DPB) ? hist[t] : 0;
    int inc = v;
#pragma unroll
    for (int off = 1; off < 64; off <<= 1) {
        int y = __shfl_up(inc, off);
        if (lane >= off) inc += y;
    }
    if (t < DPB && lane == 63) wsum_s[w] = inc;
    __syncthreads();
    int excl = ((t < DPB && w == 1) ? wsum_s[0] : 0) + inc - v;
    if (valid) {
        int gd = d0 + t;
        offsets[gd] = cbase + excl;
        if (fits) cstage[excl] = gd; else csr_src[cbase + excl] = gd;  // self loop
    }
    __syncthreads();                     // all scan reads of hist done
    if (t < DPB) hist[t] = excl + (valid ? 1 : 0);   // cursor past self loop
    __syncthreads();
    for (int i = t; i < ecnt; i += 256) {
        unsigned p = stg[sb + i];
        int pos = atomicAdd(&hist[p >> 17], 1);
        int src = (int)(p & 0x1FFFF);
        if (fits) cstage[pos] = src; else csr_src[cbase + pos] = src;
    }
    __syncthreads();
    if (fits)
        for (int i = t; i < total; i += 256) csr_src[cbase + i] = cstage[i];
}

// ---------------- K6: gather + softmax-avg + bias/relu + FC + log_softmax ------
__global__ __launch_bounds__(256) void k_gather(
    const __hip_bfloat162* __restrict__ h, const float* __restrict__ a_src,
    const float* __restrict__ a_dst, const int* __restrict__ offsets,
    const int* __restrict__ csr_src, const float* __restrict__ bias,
    const float* __restrict__ fc_w, const float* __restrict__ fc_b,
    float* __restrict__ out) {
    int t = threadIdx.x;
    int q = t & 31;
    int d = blockIdx.x * 8 + (t >> 5);
    if (d >= N_NODES) return;
    int head = q >> 2;
    int c0 = q * 4;
    int beg = offsets[d], end = offsets[d + 1];
    float ad = a_dst[d * HEADS + head];
    float acc0 = 0.f, acc1 = 0.f, acc2 = 0.f, acc3 = 0.f, wsum = 0.f;
    int s = csr_src[beg];
    for (int j = beg; j < end; ++j) {
        int s_nx = (j + 1 < end) ? csr_src[j + 1] : s;
        float e = a_src[s * HEADS + head] + ad;
        float lr = e > 0.f ? e : NEG_SLOPE * e;
        float w = __expf(lr);
        union { uint2 u; __hip_bfloat162 bb[2]; } cv;
        cv.u = *(const uint2*)(h + (size_t)s * 64 + q * 2);
        float2 f01 = __bfloat1622float2(cv.bb[0]);
        float2 f23 = __bfloat1622float2(cv.bb[1]);
        acc0 = fmaf(w, f01.x, acc0);
        acc1 = fmaf(w, f01.y, acc1);
        acc2 = fmaf(w, f23.x, acc2);
        acc3 = fmaf(w, f23.y, acc3);
        wsum += w;
        s = s_nx;
    }
    float inv = 1.f / (wsum + 1e-16f);
    float ov0 = fmaxf(acc0 * inv + bias[c0 + 0], 0.f);
    float ov1 = fmaxf(acc1 * inv + bias[c0 + 1], 0.f);
    float ov2 = fmaxf(acc2 * inv + bias[c0 + 2], 0.f);
    float ov3 = fmaxf(acc3 * inv + bias[c0 + 3], 0.f);
    float p[5];
#pragma unroll
    for (int j = 0; j < 5; ++j) {
        p[j] = ov0 * fc_w[(c0 + 0) * 5 + j] + ov1 * fc_w[(c0 + 1) * 5 + j]
             + ov2 * fc_w[(c0 + 2) * 5 + j] + ov3 * fc_w[(c0 + 3) * 5 + j];
    }
#pragma unroll
    for (int off = 16; off >= 1; off >>= 1) {
#pragma unroll
        for (int j = 0; j < 5; ++j) p[j] += __shfl_xor(p[j], off);
    }
    if (q == 0) {
        float l[5], m = -1e30f;
#pragma unroll
        for (int j = 0; j < 5; ++j) { l[j] = p[j] + fc_b[j]; m = fmaxf(m, l[j]); }
        float sum = 0.f;
#pragma unroll
        for (int j = 0; j < 5; ++j) sum += __expf(l[j] - m);
        float ls = m + __logf(sum);
#pragma unroll
        for (int j = 0; j < 5; ++j) out[d * 5 + j] = l[j] - ls;
    }
}

extern "C" void kernel_launch(void* const* d_in, const int* in_sizes, int n_in,
                              void* d_out, int out_size, void* d_ws, size_t ws_size,
                              hipStream_t stream) {
    const float* x     = (const float*)d_in[0];
    const int*   ei    = (const int*)d_in[1];
    const float* W     = (const float*)d_in[2];
    const float* att_s = (const float*)d_in[3];
    const float* att_d = (const float*)d_in[4];
    const float* bias  = (const float*)d_in[5];
    const float* fc_w  = (const float*)d_in[6];
    const float* fc_b  = (const float*)d_in[7];
    float* out = (float*)d_out;

    char* ws = (char*)d_ws;
    size_t off = 0;
    auto carve = [&](size_t bytes) {
        void* p = ws + off;
        off = (off + bytes + 255) & ~(size_t)255;
        return p;
    };
    __hip_bfloat162* h = (__hip_bfloat162*)carve((size_t)N_NODES * HC * 2);
    float*    a_src   = (float*)   carve((size_t)N_NODES * HEADS * 4);
    float*    a_dst   = (float*)   carve((size_t)N_NODES * HEADS * 4);
    int*      bhist   = (int*)     carve((NB + 1) * 4);
    int*      sbase   = (int*)     carve((NB + 1) * 4);
    int*      gcur    = (int*)     carve((NB + 1) * 4);
    int*      offsets = (int*)     carve((size_t)(N_NODES + 1) * 4);
    unsigned* stg     = (unsigned*)carve((size_t)N_EDGES * 4);
    int*      csr_src = (int*)     carve((size_t)TOTAL_E * 4);

    k_node<<<512, 256, 0, stream>>>(x, W, att_s, att_d, h, a_src, a_dst, bhist);
    k_hist<<<240, 256, 0, stream>>>(ei, bhist);
    k_scan_top<<<1, 1024, 0, stream>>>(bhist, sbase, gcur, offsets);
    k_place<<<NCH, 256, 0, stream>>>(ei, gcur, stg);
    k_build<<<NB, 256, 0, stream>>>(stg, sbase, offsets, csr_src);
    k_gather<<<(N_NODES + 7) / 8, 256, 0, stream>>>(h, a_src, a_dst, offsets, csr_src,
                                                    bias, fc_w, fc_b, out);
}

// Round 7
// 262.281 us; speedup vs baseline: 1.0020x; 1.0020x over previous
//
#include <hip/hip_runtime.h>
#include <hip/hip_bf16.h>
#include <math.h>

#define N_NODES 100000
#define N_EDGES 1600000
#define HEADS 8
#define CH 16
#define HC 128
#define TOTAL_E (N_EDGES + N_NODES)
#define LOG2E 1.44269504f

#define DPB 128                          // dests per bucket
#define NB  ((N_NODES + DPB - 1) / DPB)  // 782 buckets
#define NCH 256                          // place chunks (1.6M/256 = 6250 exact)
#define EPC (N_EDGES / NCH)
#define NNODE 384                        // k_prep blocks doing node transform
#define NHIST 128                        // k_prep blocks doing histogram
#define EPH (N_EDGES / NHIST)            // 12500 exact
#define CAPS 4096                        // per-bucket LDS CSR stage (avg ~2174)
#define PAD 16                           // ints per padded atomic slot (64 B)

// ============ K1: node transform ∥ bucket histogram (+last-block scan) ========
// blocks [0,NNODE): h = x@W (bf16), a_src/a_dst scaled by LOG2E
// blocks [NNODE,NNODE+NHIST): LDS-privatized bucket histogram -> padded-atomic
//   merge -> the LAST finisher block scans 782 totals into sbase/gcur.
// RACE FIX (R6): __syncthreads() BEFORE the done-counter increment so every
// thread's global histogram atomics are drained (vmcnt(0)) first; acq_rel on
// the counter + acquire fence on the winner before re-reading the histogram.
__global__ __launch_bounds__(256) void k_prep(
    const float* __restrict__ x, const float* __restrict__ W,
    const float* __restrict__ att_s, const float* __restrict__ att_d,
    const int* __restrict__ ei, __hip_bfloat162* __restrict__ h,
    float* __restrict__ a_src, float* __restrict__ a_dst,
    int* __restrict__ bhist_p,           // [NB+1]*PAD ints, zeroed; [NB*PAD]=ctr
    int* __restrict__ sbase,             // [NB+1]
    int* __restrict__ gcur_p) {          // [NB]*PAD
    __shared__ float sW[16 * HC];
    __shared__ int lh[NB];
    __shared__ int wsum4[4];
    __shared__ int lastFlag;
    int t = threadIdx.x;
    if (blockIdx.x < NNODE) {
        // ---- node role ----
        for (int i = t; i < 16 * HC; i += 256) sW[i] = W[i];
        __syncthreads();
        int lane = t & 63;
        int gw = blockIdx.x * 4 + (t >> 6);
        int c0 = 2 * lane;
        float as0 = att_s[c0] * LOG2E, as1 = att_s[c0 + 1] * LOG2E;
        float ad0 = att_d[c0] * LOG2E, ad1 = att_d[c0 + 1] * LOG2E;
        for (int node = gw; node < N_NODES; node += NNODE * 4) {
            float xv = 0.f;
            if (lane < 16) xv = x[node * 16 + lane];
            float acc0 = 0.f, acc1 = 0.f;
#pragma unroll
            for (int k = 0; k < 16; ++k) {
                float xk = __shfl(xv, k);
                acc0 = fmaf(xk, sW[k * HC + c0], acc0);
                acc1 = fmaf(xk, sW[k * HC + c0 + 1], acc1);
            }
            h[node * 64 + lane] = __float22bfloat162_rn(float2{acc0, acc1});
            float ps = acc0 * as0 + acc1 * as1;
            float pd = acc0 * ad0 + acc1 * ad1;
#pragma unroll
            for (int off = 4; off >= 1; off >>= 1) {
                ps += __shfl_xor(ps, off);
                pd += __shfl_xor(pd, off);
            }
            if ((lane & 7) == 0) {
                int hd = lane >> 3;
                a_src[node * HEADS + hd] = ps;
                a_dst[node * HEADS + hd] = pd;
            }
        }
    } else {
        // ---- hist role ----
        int c = blockIdx.x - NNODE;
        for (int b = t; b < NB; b += 256) lh[b] = 0;
        __syncthreads();
        int beg = c * EPH, end = beg + EPH;
        for (int e = beg + t; e < end; e += 256)
            atomicAdd(&lh[ei[N_EDGES + e] >> 7], 1);
        __syncthreads();
        for (int b = t; b < NB; b += 256)
            if (lh[b]) atomicAdd(&bhist_p[b * PAD], lh[b]);
        __syncthreads();                 // drain ALL threads' global atomics
        if (t == 0) {
            int old = __hip_atomic_fetch_add(&bhist_p[NB * PAD], 1,
                                             __ATOMIC_ACQ_REL,
                                             __HIP_MEMORY_SCOPE_AGENT);
            lastFlag = (old == NHIST - 1);
        }
        __syncthreads();
        if (!lastFlag) return;
        __threadfence();                 // acquire: see all blocks' histogram
        // ---- last finisher: exclusive scan of 782 bucket totals ----
        int lane = t & 63, wv = t >> 6;
        int i0 = t * 4;
        int v[4];
#pragma unroll
        for (int k = 0; k < 4; ++k)
            v[k] = (i0 + k < NB)
                 ? __hip_atomic_load(&bhist_p[(i0 + k) * PAD],
                                     __ATOMIC_RELAXED, __HIP_MEMORY_SCOPE_AGENT)
                 : 0;
        int s1 = v[0] + v[1], s2 = s1 + v[2], T = s2 + v[3];
        int inc = T;
#pragma unroll
        for (int off = 1; off < 64; off <<= 1) {
            int y = __shfl_up(inc, off);
            if (lane >= off) inc += y;
        }
        if (lane == 63) wsum4[wv] = inc;
        __syncthreads();
        int wbase = 0;
        for (int k = 0; k < wv; ++k) wbase += wsum4[k];
        int B = wbase + inc - T;
        int pre[4] = {0, v[0], s1, s2};
#pragma unroll
        for (int k = 0; k < 4; ++k) {
            int b = i0 + k;
            if (b < NB) { sbase[b] = B + pre[k]; gcur_p[b * PAD] = B + pre[k]; }
        }
        if (t == 0) sbase[NB] = wsum4[0] + wsum4[1] + wsum4[2] + wsum4[3];
    }
}

// ============ K2: place edges into bucket-partitioned staging ================
// 2-pass: LDS count -> one padded global atomic per (block,bucket) run
// reservation -> direct placement. Runs avg 8 edges (32 B).
__global__ __launch_bounds__(256) void k_place(const int* __restrict__ ei,
                                               int* __restrict__ gcur_p,
                                               unsigned* __restrict__ stg) {
    __shared__ int cnt[NB];
    __shared__ int curb[NB];
    int t = threadIdx.x, c = blockIdx.x;
    for (int b = t; b < NB; b += 256) cnt[b] = 0;
    __syncthreads();
    int beg = c * EPC, end = beg + EPC;
    for (int e = beg + t; e < end; e += 256)
        atomicAdd(&cnt[ei[N_EDGES + e] >> 7], 1);
    __syncthreads();
    for (int b = t; b < NB; b += 256) {
        int n = cnt[b];
        curb[b] = n ? atomicAdd(&gcur_p[b * PAD], n) : 0;
    }
    __syncthreads();
    for (int e = beg + t; e < end; e += 256) {
        unsigned src = (unsigned)ei[e];
        int dst = ei[N_EDGES + e];
        int pos = atomicAdd(&curb[dst >> 7], 1);
        stg[pos] = ((unsigned)(dst & 127) << 17) | src;   // src < 2^17
    }
}

// ============ K3: fused LDS-CSR build + gather + FC + log_softmax ============
// one block per bucket (512 thr): build dest-sorted CSR of ~2174 entries in
// LDS (self loops analytic), then 16 lane-groups of 32 gather 8 dests each.
#define EDGE_BODY(SRC) {                                                      \
    int src_ = (SRC);                                                         \
    float e_ = a_src[src_ * 8 + head] + ad;                                   \
    float el_ = fmaxf(e_, 0.2f * e_);                                         \
    float w_ = exp2f(el_);                                                    \
    union { uint2 u; __hip_bfloat162 bb[2]; } cv_;                            \
    cv_.u = *(const uint2*)(h + (size_t)src_ * 64 + q * 2);                   \
    float2 f01_ = __bfloat1622float2(cv_.bb[0]);                              \
    float2 f23_ = __bfloat1622float2(cv_.bb[1]);                              \
    acc0 = fmaf(w_, f01_.x, acc0); acc1 = fmaf(w_, f01_.y, acc1);             \
    acc2 = fmaf(w_, f23_.x, acc2); acc3 = fmaf(w_, f23_.y, acc3);             \
    wsum += w_; }

__global__ __launch_bounds__(512) void k_gather(
    const __hip_bfloat162* __restrict__ h, const float* __restrict__ a_src,
    const float* __restrict__ a_dst, const int* __restrict__ sbase,
    const unsigned* __restrict__ stg, int* __restrict__ csr_ovf,
    const float* __restrict__ bias, const float* __restrict__ fc_w,
    const float* __restrict__ fc_b, float* __restrict__ out) {
    __shared__ int hist[DPB];        // count -> cursor
    __shared__ int bs[DPB + 1];      // exclusive boundaries
    __shared__ int cstage[CAPS];
    __shared__ int w2[2];
    int b = blockIdx.x, t = threadIdx.x;
    int sb = sbase[b], ecnt = sbase[b + 1] - sb;
    int d0 = b << 7;
    int selfc = N_NODES - d0; if (selfc > DPB) selfc = DPB;
    int total = ecnt + selfc;
    bool fits = total <= CAPS;
    int* gstage = csr_ovf + sb + d0;         // exact-size overflow arena
    if (t < DPB) hist[t] = (d0 + t < N_NODES) ? 1 : 0;
    __syncthreads();
    for (int i = t; i < ecnt; i += 512) atomicAdd(&hist[stg[sb + i] >> 17], 1);
    __syncthreads();
    int lane = t & 63, wv = t >> 6;
    int v = (t < DPB) ? hist[t] : 0;
    int inc = v;
#pragma unroll
    for (int off = 1; off < 64; off <<= 1) {
        int y = __shfl_up(inc, off);
        if (lane >= off) inc += y;
    }
    if (t < DPB && lane == 63) w2[wv] = inc;
    __syncthreads();
    if (t < DPB) {
        int excl = inc - v + ((wv == 1) ? w2[0] : 0);
        bs[t] = excl;
        int gd = d0 + t;
        if (gd < N_NODES) {                       // place self loop
            if (fits) cstage[excl] = gd; else gstage[excl] = gd;
        }
    }
    if (t == 0) bs[DPB] = total;
    __syncthreads();
    if (t < DPB) hist[t] = bs[t] + ((d0 + t < N_NODES) ? 1 : 0);
    __syncthreads();
    for (int i = t; i < ecnt; i += 512) {
        unsigned u = stg[sb + i];
        int pos = atomicAdd(&hist[u >> 17], 1);
        int src = (int)(u & 0x1FFFF);
        if (fits) cstage[pos] = src; else gstage[pos] = src;
    }
    __syncthreads();
    // ---- gather phase ----
    int q = t & 31, g = t >> 5;           // 16 groups of 32 lanes
    int head = q >> 2, c0 = q * 4;
    float b0 = bias[c0], b1 = bias[c0 + 1], b2 = bias[c0 + 2], b3 = bias[c0 + 3];
    float fw[4][5], fb[5];
#pragma unroll
    for (int k = 0; k < 4; ++k)
#pragma unroll
        for (int j = 0; j < 5; ++j) fw[k][j] = fc_w[(c0 + k) * 5 + j];
#pragma unroll
    for (int j = 0; j < 5; ++j) fb[j] = fc_b[j];
    for (int l8 = 0; l8 < 8; ++l8) {
        int l = g * 8 + l8;
        int gd = d0 + l;
        if (gd >= N_NODES) break;
        int beg = bs[l], end = bs[l + 1];
        float ad = a_dst[gd * 8 + head];
        float acc0 = 0.f, acc1 = 0.f, acc2 = 0.f, acc3 = 0.f, wsum = 0.f;
        if (fits) { for (int j = beg; j < end; ++j) EDGE_BODY(cstage[j]) }
        else      { for (int j = beg; j < end; ++j) EDGE_BODY(gstage[j]) }
        float inv = 1.f / (wsum + 1e-16f);
        float ov0 = fmaxf(acc0 * inv + b0, 0.f);
        float ov1 = fmaxf(acc1 * inv + b1, 0.f);
        float ov2 = fmaxf(acc2 * inv + b2, 0.f);
        float ov3 = fmaxf(acc3 * inv + b3, 0.f);
        float p[5];
#pragma unroll
        for (int j = 0; j < 5; ++j)
            p[j] = ov0 * fw[0][j] + ov1 * fw[1][j] + ov2 * fw[2][j] + ov3 * fw[3][j];
#pragma unroll
        for (int off = 16; off >= 1; off >>= 1) {
#pragma unroll
            for (int j = 0; j < 5; ++j) p[j] += __shfl_xor(p[j], off);
        }
        if (q == 0) {
            float lg[5], m = -1e30f;
#pragma unroll
            for (int j = 0; j < 5; ++j) { lg[j] = p[j] + fb[j]; m = fmaxf(m, lg[j]); }
            float sum = 0.f;
#pragma unroll
            for (int j = 0; j < 5; ++j) sum += __expf(lg[j] - m);
            float ls = m + __logf(sum);
#pragma unroll
            for (int j = 0; j < 5; ++j) out[gd * 5 + j] = lg[j] - ls;
        }
    }
}

extern "C" void kernel_launch(void* const* d_in, const int* in_sizes, int n_in,
                              void* d_out, int out_size, void* d_ws, size_t ws_size,
                              hipStream_t stream) {
    const float* x     = (const float*)d_in[0];
    const int*   ei    = (const int*)d_in[1];
    const float* W     = (const float*)d_in[2];
    const float* att_s = (const float*)d_in[3];
    const float* att_d = (const float*)d_in[4];
    const float* bias  = (const float*)d_in[5];
    const float* fc_w  = (const float*)d_in[6];
    const float* fc_b  = (const float*)d_in[7];
    float* out = (float*)d_out;

    char* ws = (char*)d_ws;
    size_t off = 0;
    auto carve = [&](size_t bytes) {
        void* p = ws + off;
        off = (off + bytes + 255) & ~(size_t)255;
        return p;
    };
    __hip_bfloat162* h = (__hip_bfloat162*)carve((size_t)N_NODES * HC * 2);
    float*    a_src   = (float*)   carve((size_t)N_NODES * HEADS * 4);
    float*    a_dst   = (float*)   carve((size_t)N_NODES * HEADS * 4);
    int*      bhist_p = (int*)     carve((size_t)(NB + 1) * PAD * 4);
    int*      sbase   = (int*)     carve((NB + 1) * 4);
    int*      gcur_p  = (int*)     carve((size_t)NB * PAD * 4);
    unsigned* stg     = (unsigned*)carve((size_t)N_EDGES * 4);
    int*      csr_ovf = (int*)     carve((size_t)TOTAL_E * 4);

    hipMemsetAsync(bhist_p, 0, (size_t)(NB + 1) * PAD * 4, stream);
    k_prep<<<NNODE + NHIST, 256, 0, stream>>>(x, W, att_s, att_d, ei, h,
                                              a_src, a_dst, bhist_p, sbase, gcur_p);
    k_place<<<NCH, 256, 0, stream>>>(ei, gcur_p, stg);
    k_gather<<<NB, 512, 0, stream>>>(h, a_src, a_dst, sbase, stg, csr_ovf,
                                     bias, fc_w, fc_b, out);
}

// Round 8
// 228.473 us; speedup vs baseline: 1.1503x; 1.1480x over previous
//
#include <hip/hip_runtime.h>
#include <hip/hip_bf16.h>
#include <math.h>

#define N_NODES 100000
#define N_EDGES 1600000
#define HEADS 8
#define HC 128
#define LOG2E 1.44269504f

#define DPB 64                    // dests per bucket
#define NB 1563                   // ceil(100000/64)
#define NBP (NB + 1)              // offsets row width (with end sentinel)
#define NCH 256                   // edge chunks (1.6M/256 = 6250 exact)
#define EPC (N_EDGES / NCH)       // 6250
#define CAPS 2048                 // per-bucket LDS cap (lambda~1024, sigma~32)

// ============ K1: node transform: h = x@W (bf16), a_src/a_dst (xLOG2E) =======
__global__ __launch_bounds__(256) void k_node(
    const float* __restrict__ x, const float* __restrict__ W,
    const float* __restrict__ att_s, const float* __restrict__ att_d,
    __hip_bfloat162* __restrict__ h, float* __restrict__ a_src,
    float* __restrict__ a_dst) {
    __shared__ float sW[16 * HC];
    int t = threadIdx.x;
    for (int i = t; i < 16 * HC; i += 256) sW[i] = W[i];
    __syncthreads();
    int lane = t & 63;
    int gw = blockIdx.x * 4 + (t >> 6);
    int nw = gridDim.x * 4;
    int c0 = 2 * lane;
    float as0 = att_s[c0] * LOG2E, as1 = att_s[c0 + 1] * LOG2E;
    float ad0 = att_d[c0] * LOG2E, ad1 = att_d[c0 + 1] * LOG2E;
    for (int node = gw; node < N_NODES; node += nw) {
        float xv = 0.f;
        if (lane < 16) xv = x[node * 16 + lane];
        float acc0 = 0.f, acc1 = 0.f;
#pragma unroll
        for (int k = 0; k < 16; ++k) {
            float xk = __shfl(xv, k);
            acc0 = fmaf(xk, sW[k * HC + c0], acc0);
            acc1 = fmaf(xk, sW[k * HC + c0 + 1], acc1);
        }
        h[node * 64 + lane] = __float22bfloat162_rn(float2{acc0, acc1});
        float ps = acc0 * as0 + acc1 * as1;
        float pd = acc0 * ad0 + acc1 * ad1;
#pragma unroll
        for (int off = 4; off >= 1; off >>= 1) {
            ps += __shfl_xor(ps, off);
            pd += __shfl_xor(pd, off);
        }
        if ((lane & 7) == 0) {
            int hd = lane >> 3;
            a_src[node * HEADS + hd] = ps;
            a_dst[node * HEADS + hd] = pd;
        }
    }
}

// ============ K2: per-chunk counting sort (LDS only, zero global atomics) ====
// block c sorts its 6250 edges by bucket in LDS, writes them bucket-contiguous
// to stg[c*EPC ...] (coalesced) plus the per-chunk exclusive offsets row.
__global__ __launch_bounds__(512) void k_csort(const int* __restrict__ ei,
                                               int* __restrict__ offs,
                                               unsigned* __restrict__ stg) {
    __shared__ int hist[2048];          // padded NB; count -> excl -> cursor
    __shared__ int ws8[8];
    __shared__ unsigned entries[EPC];
    int t = threadIdx.x, c = blockIdx.x;
    hist[t] = 0; hist[t + 512] = 0; hist[t + 1024] = 0; hist[t + 1536] = 0;
    __syncthreads();
    int beg = c * EPC, end = beg + EPC;
    for (int e = beg + t; e < end; e += 512)
        atomicAdd(&hist[ei[N_EDGES + e] >> 6], 1);
    __syncthreads();
    // exclusive scan over 2048 via 4-elem serial + 512-thread shuffle scan
    int i0 = 4 * t;
    int v0 = hist[i0], v1 = hist[i0 + 1], v2 = hist[i0 + 2], v3 = hist[i0 + 3];
    int s1 = v0 + v1, s2 = s1 + v2, T = s2 + v3;
    int lane = t & 63, wv = t >> 6;
    int inc = T;
#pragma unroll
    for (int off = 1; off < 64; off <<= 1) {
        int y = __shfl_up(inc, off);
        if (lane >= off) inc += y;
    }
    if (lane == 63) ws8[wv] = inc;
    __syncthreads();
    int wbase = 0;
    for (int k = 0; k < wv; ++k) wbase += ws8[k];
    int e0 = wbase + inc - T;
    hist[i0] = e0; hist[i0 + 1] = e0 + v0;
    hist[i0 + 2] = e0 + s1; hist[i0 + 3] = e0 + s2;
    __syncthreads();
    // write offsets row (exclusive starts within chunk)
    int row = c * NBP;
    for (int b = t; b < NB; b += 512) offs[row + b] = hist[b];
    if (t == 0) offs[row + NB] = EPC;
    __syncthreads();
    // place into LDS (hist becomes cursor)
    for (int e = beg + t; e < end; e += 512) {
        int src = ei[e], dst = ei[N_EDGES + e];
        int pos = atomicAdd(&hist[dst >> 6], 1);
        entries[pos] = ((unsigned)(dst & 63) << 17) | (unsigned)src;  // src<2^17
    }
    __syncthreads();
    unsigned* so = stg + beg;
    for (int i = t; i < EPC; i += 512) so[i] = entries[i];   // coalesced
}

// ============ K3: gather: segments -> LDS dest-sort -> softmax-avg -> FC =====
#define EDGE_BODY(SRC) {                                                      \
    int src_ = (SRC);                                                         \
    float e_ = a_src[src_ * 8 + head] + ad;                                   \
    float el_ = fmaxf(e_, 0.2f * e_);                                         \
    float w_ = exp2f(el_);                                                    \
    union { uint2 u; __hip_bfloat162 bb[2]; } cv_;                            \
    cv_.u = *(const uint2*)(h + (size_t)src_ * 64 + q * 2);                   \
    float2 f01_ = __bfloat1622float2(cv_.bb[0]);                              \
    float2 f23_ = __bfloat1622float2(cv_.bb[1]);                              \
    acc0 = fmaf(w_, f01_.x, acc0); acc1 = fmaf(w_, f01_.y, acc1);             \
    acc2 = fmaf(w_, f23_.x, acc2); acc3 = fmaf(w_, f23_.y, acc3);             \
    wsum += w_; }

__global__ __launch_bounds__(256) void k_gather(
    const __hip_bfloat162* __restrict__ h, const float* __restrict__ a_src,
    const float* __restrict__ a_dst, const int* __restrict__ offs,
    const unsigned* __restrict__ stg, const float* __restrict__ bias,
    const float* __restrict__ fc_w, const float* __restrict__ fc_b,
    float* __restrict__ out) {
    __shared__ unsigned estage[CAPS];
    __shared__ int cstage[CAPS];
    __shared__ int hist[DPB];
    __shared__ int bs[DPB + 1];
    __shared__ int ws4[4];
    __shared__ int tot_s;
    int b = blockIdx.x, t = threadIdx.x;
    int d0 = b * DPB;
    // phase 1: this bucket's segment length in each chunk (t == chunk id)
    int o0 = offs[t * NBP + b];
    int len = offs[t * NBP + b + 1] - o0;
    int lane = t & 63, wv = t >> 6;
    int inc = len;
#pragma unroll
    for (int off = 1; off < 64; off <<= 1) {
        int y = __shfl_up(inc, off);
        if (lane >= off) inc += y;
    }
    if (lane == 63) ws4[wv] = inc;
    __syncthreads();
    int wbase = 0;
    for (int k = 0; k < wv; ++k) wbase += ws4[k];
    int myb = wbase + inc - len;
    if (t == 255) tot_s = myb + len;
    __syncthreads();
    int tot = tot_s;
    // phase 2: copy segments into LDS
    const unsigned* gseg = stg + t * EPC + o0;
    for (int k = 0; k < len; ++k) estage[myb + k] = gseg[k];
    if (t < DPB) hist[t] = (d0 + t < N_NODES) ? 1 : 0;   // self loop pre-count
    __syncthreads();
    // phase 3: dest histogram
    for (int i = t; i < tot; i += 256) atomicAdd(&hist[estage[i] >> 17], 1);
    __syncthreads();
    // phase 4: 64-scan by wave 0, place self loops, init cursors
    if (t < 64) {
        int v = hist[t];
        int iv = v;
#pragma unroll
        for (int off = 1; off < 64; off <<= 1) {
            int y = __shfl_up(iv, off);
            if (t >= off) iv += y;
        }
        int excl = iv - v;
        bs[t] = excl;
        if (t == 63) bs[64] = iv;
        int gd = d0 + t;
        bool val = gd < N_NODES;
        if (val) cstage[excl] = gd;
        hist[t] = excl + (val ? 1 : 0);
    }
    __syncthreads();
    // phase 5: place edges dest-sorted
    for (int i = t; i < tot; i += 256) {
        unsigned u = estage[i];
        int pos = atomicAdd(&hist[u >> 17], 1);
        cstage[pos] = (int)(u & 0x1FFFF);
    }
    __syncthreads();
    // phase 6: gather + bias/relu + FC + log_softmax (8 groups x 8 dests)
    int q = t & 31, g = t >> 5;
    int head = q >> 2, c0 = q * 4;
    float b0 = bias[c0], b1 = bias[c0 + 1], b2 = bias[c0 + 2], b3 = bias[c0 + 3];
    float fw[4][5], fb[5];
#pragma unroll
    for (int k = 0; k < 4; ++k)
#pragma unroll
        for (int j = 0; j < 5; ++j) fw[k][j] = fc_w[(c0 + k) * 5 + j];
#pragma unroll
    for (int j = 0; j < 5; ++j) fb[j] = fc_b[j];
    for (int l8 = 0; l8 < 8; ++l8) {
        int l = g * 8 + l8;
        int gd = d0 + l;
        if (gd >= N_NODES) break;
        int beg = bs[l], end = bs[l + 1];
        float ad = a_dst[gd * 8 + head];
        float acc0 = 0.f, acc1 = 0.f, acc2 = 0.f, acc3 = 0.f, wsum = 0.f;
        for (int j = beg; j < end; ++j) EDGE_BODY(cstage[j])
        float inv = 1.f / (wsum + 1e-16f);
        float ov0 = fmaxf(acc0 * inv + b0, 0.f);
        float ov1 = fmaxf(acc1 * inv + b1, 0.f);
        float ov2 = fmaxf(acc2 * inv + b2, 0.f);
        float ov3 = fmaxf(acc3 * inv + b3, 0.f);
        float p[5];
#pragma unroll
        for (int j = 0; j < 5; ++j)
            p[j] = ov0 * fw[0][j] + ov1 * fw[1][j] + ov2 * fw[2][j] + ov3 * fw[3][j];
#pragma unroll
        for (int off = 16; off >= 1; off >>= 1) {
#pragma unroll
            for (int j = 0; j < 5; ++j) p[j] += __shfl_xor(p[j], off);
        }
        if (q == 0) {
            float lg[5], m = -1e30f;
#pragma unroll
            for (int j = 0; j < 5; ++j) { lg[j] = p[j] + fb[j]; m = fmaxf(m, lg[j]); }
            float sum = 0.f;
#pragma unroll
            for (int j = 0; j < 5; ++j) sum += __expf(lg[j] - m);
            float ls = m + __logf(sum);
#pragma unroll
            for (int j = 0; j < 5; ++j) out[gd * 5 + j] = lg[j] - ls;
        }
    }
}

extern "C" void kernel_launch(void* const* d_in, const int* in_sizes, int n_in,
                              void* d_out, int out_size, void* d_ws, size_t ws_size,
                              hipStream_t stream) {
    const float* x     = (const float*)d_in[0];
    const int*   ei    = (const int*)d_in[1];
    const float* W     = (const float*)d_in[2];
    const float* att_s = (const float*)d_in[3];
    const float* att_d = (const float*)d_in[4];
    const float* bias  = (const float*)d_in[5];
    const float* fc_w  = (const float*)d_in[6];
    const float* fc_b  = (const float*)d_in[7];
    float* out = (float*)d_out;

    char* ws = (char*)d_ws;
    size_t off = 0;
    auto carve = [&](size_t bytes) {
        void* p = ws + off;
        off = (off + bytes + 255) & ~(size_t)255;
        return p;
    };
    __hip_bfloat162* h = (__hip_bfloat162*)carve((size_t)N_NODES * HC * 2);
    float*    a_src = (float*)   carve((size_t)N_NODES * HEADS * 4);
    float*    a_dst = (float*)   carve((size_t)N_NODES * HEADS * 4);
    int*      offs  = (int*)     carve((size_t)NCH * NBP * 4);     // 1.6 MB
    unsigned* stg   = (unsigned*)carve((size_t)N_EDGES * 4);       // 6.4 MB

    k_node<<<512, 256, 0, stream>>>(x, W, att_s, att_d, h, a_src, a_dst);
    k_csort<<<NCH, 512, 0, stream>>>(ei, offs, stg);
    k_gather<<<NB, 256, 0, stream>>>(h, a_src, a_dst, offs, stg,
                                     bias, fc_w, fc_b, out);
}

// Round 9
// 214.557 us; speedup vs baseline: 1.2249x; 1.0649x over previous
//
#include <hip/hip_runtime.h>
#include <hip/hip_bf16.h>
#include <math.h>

#define N_NODES 100000
#define N_EDGES 1600000
#define HEADS 8
#define HC 128
#define LOG2E 1.44269504f

#define DPB 64                    // dests per bucket
#define NB 1563                   // ceil(100000/64)
#define NBP (NB + 1)              // offsets rows (with end sentinel)
#define NCH 256                   // edge chunks (1.6M/256 = 6250 exact)
#define EPC (N_EDGES / NCH)       // 6250
#define CAPS 2048                 // per-bucket LDS cap (mean ~1088, max ~1300)
#define NNODE 512                 // node-role blocks in k_prep

// ============ K1: fused node transform (blocks >= NCH) + counting sort =======
// csort role (blocks 0..NCH): LDS counting-sort 6250 edges by 64-dest bucket,
//   write bucket-contiguous packed edges + per-chunk offsets row (coalesced).
// node role: h = x@W (bf16), a_src/a_dst (pre-scaled by LOG2E for exp2).
__global__ __launch_bounds__(512) void k_prep(
    const float* __restrict__ x, const float* __restrict__ W,
    const float* __restrict__ att_s, const float* __restrict__ att_d,
    const int* __restrict__ ei, __hip_bfloat162* __restrict__ h,
    float* __restrict__ a_src, float* __restrict__ a_dst,
    int* __restrict__ offs, unsigned* __restrict__ stg) {
    __shared__ int smem[2048 + EPC];     // csort: hist[2048] + entries[EPC]
    __shared__ int ws8[8];               // node: reuses smem[0..2048) as sW
    int t = threadIdx.x;
    if (blockIdx.x >= NCH) {
        // ---- node role ----
        float* sW = (float*)smem;
        for (int i = t; i < 16 * HC; i += 512) sW[i] = W[i];
        __syncthreads();
        int lane = t & 63, wv = t >> 6;
        int gw = (blockIdx.x - NCH) * 8 + wv;
        int c0 = 2 * lane;
        float as0 = att_s[c0] * LOG2E, as1 = att_s[c0 + 1] * LOG2E;
        float ad0 = att_d[c0] * LOG2E, ad1 = att_d[c0 + 1] * LOG2E;
        for (int node = gw; node < N_NODES; node += NNODE * 8) {
            float xv = 0.f;
            if (lane < 16) xv = x[node * 16 + lane];
            float acc0 = 0.f, acc1 = 0.f;
#pragma unroll
            for (int k = 0; k < 16; ++k) {
                float xk = __shfl(xv, k);
                acc0 = fmaf(xk, sW[k * HC + c0], acc0);
                acc1 = fmaf(xk, sW[k * HC + c0 + 1], acc1);
            }
            h[node * 64 + lane] = __float22bfloat162_rn(float2{acc0, acc1});
            float ps = acc0 * as0 + acc1 * as1;
            float pd = acc0 * ad0 + acc1 * ad1;
#pragma unroll
            for (int off = 4; off >= 1; off >>= 1) {
                ps += __shfl_xor(ps, off);
                pd += __shfl_xor(pd, off);
            }
            if ((lane & 7) == 0) {
                int hd = lane >> 3;
                a_src[node * HEADS + hd] = ps;
                a_dst[node * HEADS + hd] = pd;
            }
        }
    } else {
        // ---- csort role ----
        int* hist = smem;                // [2048]
        unsigned* entries = (unsigned*)(smem + 2048);   // [EPC]
        int c = blockIdx.x;
        hist[t] = 0; hist[t + 512] = 0; hist[t + 1024] = 0; hist[t + 1536] = 0;
        __syncthreads();
        int beg = c * EPC, end = beg + EPC;
        for (int e = beg + t; e < end; e += 512)
            atomicAdd(&hist[ei[N_EDGES + e] >> 6], 1);
        __syncthreads();
        int i0 = 4 * t;
        int v0 = hist[i0], v1 = hist[i0 + 1], v2 = hist[i0 + 2], v3 = hist[i0 + 3];
        int s1 = v0 + v1, s2 = s1 + v2, T = s2 + v3;
        int lane = t & 63, wv = t >> 6;
        int inc = T;
#pragma unroll
        for (int off = 1; off < 64; off <<= 1) {
            int y = __shfl_up(inc, off);
            if (lane >= off) inc += y;
        }
        if (lane == 63) ws8[wv] = inc;
        __syncthreads();
        int wbase = 0;
        for (int k = 0; k < wv; ++k) wbase += ws8[k];
        int e0 = wbase + inc - T;
        hist[i0] = e0; hist[i0 + 1] = e0 + v0;
        hist[i0 + 2] = e0 + s1; hist[i0 + 3] = e0 + s2;
        __syncthreads();
        int row = c * NBP;
        for (int b = t; b < NB; b += 512) offs[row + b] = hist[b];
        if (t == 0) offs[row + NB] = EPC;
        __syncthreads();
        for (int e = beg + t; e < end; e += 512) {
            int src = ei[e], dst = ei[N_EDGES + e];
            int pos = atomicAdd(&hist[dst >> 6], 1);
            entries[pos] = ((unsigned)(dst & 63) << 17) | (unsigned)src;
        }
        __syncthreads();
        unsigned* so = stg + beg;
        for (int i = t; i < EPC; i += 512) so[i] = entries[i];
    }
}

// ============ K2: transpose offs [NCH][NBP] -> offsT [NBP][NCH] ==============
__global__ __launch_bounds__(256) void k_tr(const int* __restrict__ offs,
                                            int* __restrict__ offsT) {
    __shared__ int tile[64][65];
    int b0 = (blockIdx.x >> 2) * 64;      // 25 b-tiles
    int c0 = (blockIdx.x & 3) * 64;       // 4 c-tiles
    int t = threadIdx.x;
    for (int i = t; i < 4096; i += 256) {
        int cc = i >> 6, bb = i & 63;
        int b = b0 + bb;
        tile[bb][cc] = (b < NBP) ? offs[(c0 + cc) * NBP + b] : 0;
    }
    __syncthreads();
    for (int i = t; i < 4096; i += 256) {
        int bb = i >> 6, cc = i & 63;
        int b = b0 + bb;
        if (b < NBP) offsT[b * NCH + c0 + cc] = tile[bb][cc];
    }
}

// ============ K3: gather: coalesced seg copy -> LDS dest-sort -> FC ==========
#define EDGE_BODY(SRC) {                                                      \
    int src_ = (SRC);                                                         \
    float e_ = a_src[src_ * 8 + head] + ad;                                   \
    float el_ = fmaxf(e_, 0.2f * e_);                                         \
    float w_ = exp2f(el_);                                                    \
    union { uint2 u; __hip_bfloat162 bb_[2]; } cv_;                           \
    cv_.u = *(const uint2*)(h + (size_t)src_ * 64 + q * 2);                   \
    float2 f01_ = __bfloat1622float2(cv_.bb_[0]);                             \
    float2 f23_ = __bfloat1622float2(cv_.bb_[1]);                             \
    acc0 = fmaf(w_, f01_.x, acc0); acc1 = fmaf(w_, f01_.y, acc1);             \
    acc2 = fmaf(w_, f23_.x, acc2); acc3 = fmaf(w_, f23_.y, acc3);             \
    wsum += w_; }

__global__ __launch_bounds__(256) void k_gather(
    const __hip_bfloat162* __restrict__ h, const float* __restrict__ a_src,
    const float* __restrict__ a_dst, const int* __restrict__ offsT,
    const unsigned* __restrict__ stg, const float* __restrict__ bias,
    const float* __restrict__ fc_w, const float* __restrict__ fc_b,
    float* __restrict__ out) {
    __shared__ unsigned estage[CAPS];
    __shared__ int cstage[CAPS];
    __shared__ int o0_s[NCH];
    __shared__ int myb_s[NCH + 1];
    __shared__ int hist[DPB];
    __shared__ int bs[DPB + 1];
    __shared__ int ws4[4];
    int b = blockIdx.x, t = threadIdx.x;
    int d0 = b * DPB;
    // phase 1: segment starts/lengths (coalesced rows of offsT)
    int o0 = offsT[b * NCH + t];
    int len = offsT[(b + 1) * NCH + t] - o0;
    o0_s[t] = o0;
    int lane = t & 63, wv = t >> 6;
    int inc = len;
#pragma unroll
    for (int off = 1; off < 64; off <<= 1) {
        int y = __shfl_up(inc, off);
        if (lane >= off) inc += y;
    }
    if (lane == 63) ws4[wv] = inc;
    __syncthreads();
    int wbase = 0;
    for (int k = 0; k < wv; ++k) wbase += ws4[k];
    myb_s[t] = wbase + inc - len;
    if (t == 255) myb_s[NCH] = wbase + inc;
    if (t < DPB) hist[t] = (d0 + t < N_NODES) ? 1 : 0;   // self loop pre-count
    __syncthreads();
    int tot = myb_s[NCH];
    // phase 2: cooperative coalesced copy (binary search chunk per entry)
    for (int i = t; i < tot; i += 256) {
        int lo = 0, hi = NCH - 1;
#pragma unroll
        for (int s = 0; s < 8; ++s) {
            int mid = (lo + hi + 1) >> 1;
            if (myb_s[mid] <= i) lo = mid; else hi = mid - 1;
        }
        estage[i] = stg[lo * EPC + o0_s[lo] + (i - myb_s[lo])];
    }
    __syncthreads();
    // phase 3: dest histogram
    for (int i = t; i < tot; i += 256) atomicAdd(&hist[estage[i] >> 17], 1);
    __syncthreads();
    // phase 4: 64-scan by wave 0, place self loops, init cursors
    if (t < 64) {
        int v = hist[t];
        int iv = v;
#pragma unroll
        for (int off = 1; off < 64; off <<= 1) {
            int y = __shfl_up(iv, off);
            if (t >= off) iv += y;
        }
        int excl = iv - v;
        bs[t] = excl;
        if (t == 63) bs[64] = iv;
        int gd = d0 + t;
        bool val = gd < N_NODES;
        if (val) cstage[excl] = gd;
        hist[t] = excl + (val ? 1 : 0);
    }
    __syncthreads();
    // phase 5: place edges dest-sorted
    for (int i = t; i < tot; i += 256) {
        unsigned u = estage[i];
        int pos = atomicAdd(&hist[u >> 17], 1);
        cstage[pos] = (int)(u & 0x1FFFF);
    }
    __syncthreads();
    // phase 6: gather + bias/relu + FC + log_softmax (8 groups x 8 dests)
    int q = t & 31, g = t >> 5;
    int head = q >> 2, c0 = q * 4;
    float b0 = bias[c0], b1 = bias[c0 + 1], b2 = bias[c0 + 2], b3 = bias[c0 + 3];
    float fw[4][5], fb[5];
#pragma unroll
    for (int k = 0; k < 4; ++k)
#pragma unroll
        for (int j = 0; j < 5; ++j) fw[k][j] = fc_w[(c0 + k) * 5 + j];
#pragma unroll
    for (int j = 0; j < 5; ++j) fb[j] = fc_b[j];
    for (int l8 = 0; l8 < 8; ++l8) {
        int l = g * 8 + l8;
        int gd = d0 + l;
        if (gd >= N_NODES) break;
        int beg = bs[l], end = bs[l + 1];
        float ad = a_dst[gd * 8 + head];
        float acc0 = 0.f, acc1 = 0.f, acc2 = 0.f, acc3 = 0.f, wsum = 0.f;
        for (int j = beg; j < end; ++j) EDGE_BODY(cstage[j])
        float inv = 1.f / (wsum + 1e-16f);
        float ov0 = fmaxf(acc0 * inv + b0, 0.f);
        float ov1 = fmaxf(acc1 * inv + b1, 0.f);
        float ov2 = fmaxf(acc2 * inv + b2, 0.f);
        float ov3 = fmaxf(acc3 * inv + b3, 0.f);
        float p[5];
#pragma unroll
        for (int j = 0; j < 5; ++j)
            p[j] = ov0 * fw[0][j] + ov1 * fw[1][j] + ov2 * fw[2][j] + ov3 * fw[3][j];
#pragma unroll
        for (int off = 16; off >= 1; off >>= 1) {
#pragma unroll
            for (int j = 0; j < 5; ++j) p[j] += __shfl_xor(p[j], off);
        }
        if (q == 0) {
            float lg[5], m = -1e30f;
#pragma unroll
            for (int j = 0; j < 5; ++j) { lg[j] = p[j] + fb[j]; m = fmaxf(m, lg[j]); }
            float sum = 0.f;
#pragma unroll
            for (int j = 0; j < 5; ++j) sum += __expf(lg[j] - m);
            float ls = m + __logf(sum);
#pragma unroll
            for (int j = 0; j < 5; ++j) out[gd * 5 + j] = lg[j] - ls;
        }
    }
}

extern "C" void kernel_launch(void* const* d_in, const int* in_sizes, int n_in,
                              void* d_out, int out_size, void* d_ws, size_t ws_size,
                              hipStream_t stream) {
    const float* x     = (const float*)d_in[0];
    const int*   ei    = (const int*)d_in[1];
    const float* W     = (const float*)d_in[2];
    const float* att_s = (const float*)d_in[3];
    const float* att_d = (const float*)d_in[4];
    const float* bias  = (const float*)d_in[5];
    const float* fc_w  = (const float*)d_in[6];
    const float* fc_b  = (const float*)d_in[7];
    float* out = (float*)d_out;

    char* ws = (char*)d_ws;
    size_t off = 0;
    auto carve = [&](size_t bytes) {
        void* p = ws + off;
        off = (off + bytes + 255) & ~(size_t)255;
        return p;
    };
    __hip_bfloat162* h = (__hip_bfloat162*)carve((size_t)N_NODES * HC * 2);
    float*    a_src = (float*)   carve((size_t)N_NODES * HEADS * 4);
    float*    a_dst = (float*)   carve((size_t)N_NODES * HEADS * 4);
    int*      offs  = (int*)     carve((size_t)NCH * NBP * 4);
    int*      offsT = (int*)     carve((size_t)NBP * NCH * 4);
    unsigned* stg   = (unsigned*)carve((size_t)N_EDGES * 4);

    k_prep<<<NCH + NNODE, 512, 0, stream>>>(x, W, att_s, att_d, ei, h,
                                            a_src, a_dst, offs, stg);
    k_tr<<<100, 256, 0, stream>>>(offs, offsT);
    k_gather<<<NB, 256, 0, stream>>>(h, a_src, a_dst, offsT, stg,
                                     bias, fc_w, fc_b, out);
}